// Round 1
// baseline (544.391 us; speedup 1.0000x reference)
//
#include <hip/hip_runtime.h>
#include <stdint.h>

#define EPSV 1e-5f

// c8-chunked activation layout: elem = cc*278784 + ((b*66+y)*66+x)*8 + (c&7)
#define CPLANE 278784   // 8*66*66*8 elems per channel-chunk plane

using floatx4 = __attribute__((ext_vector_type(4))) float;
using short8  = __attribute__((ext_vector_type(8))) short;

// async global->LDS 16B DMA: data lands at ldsbase + lane*16
#define GLD(gp, lp) __builtin_amdgcn_global_load_lds( \
    (const __attribute__((address_space(1))) void*)(gp), \
    (__attribute__((address_space(3))) void*)(lp), 16, 0, 0)

__device__ __forceinline__ unsigned short f2bf(float f) {
  union { float f; unsigned int u; } x; x.f = f;
  unsigned int r = x.u + 0x7fffu + ((x.u >> 16) & 1u);  // RNE
  return (unsigned short)(r >> 16);
}

// ---------------------------------------------------------------------------
// Zero the halo border of both padded c8 buffers (2.13 MB each).
// ---------------------------------------------------------------------------
__global__ __launch_bounds__(256) void border_zero_kernel(
    unsigned short* __restrict__ Xp0, unsigned short* __restrict__ Xp1) {
  int idx = blockIdx.x * 256 + threadIdx.x;   // 520*256 = 133120 = 8*64*260
  int k = idx % 260;
  int rest = idx / 260;
  int cc = rest & 63;
  int b = rest >> 6;
  int py, px;
  if (k < 66)       { py = 0;  px = k; }
  else if (k < 132) { py = 65; px = k - 66; }
  else { int k2 = k - 132; py = 1 + (k2 >> 1); px = (k2 & 1) ? 65 : 0; }
  int off = cc * CPLANE + ((b * 66 + py) * 66 + px) * 8;
  short8 z = {};
  *(short8*)(Xp0 + off) = z;
  *(short8*)(Xp1 + off) = z;
}

// ---------------------------------------------------------------------------
// Upsample (align-corners bilinear 32->64) + alpha*xm fuse -> bf16 c8 layout.
// ---------------------------------------------------------------------------
__global__ __launch_bounds__(256) void fuse_upsample_kernel(
    const float* __restrict__ xt, const float* __restrict__ xm,
    const float* __restrict__ alpha, unsigned short* __restrict__ Xp) {
  __shared__ float sm[32 * 66];        // xm tile [c][x], pad 66
  __shared__ float st[2 * 32 * 34];    // xt rows [h][c][x0..31], pad 34

  const int tid = threadIdx.x;
  const int ct = blockIdx.x & 15;          // channel tile (32 ch)
  const int y  = (blockIdx.x >> 4) & 63;
  const int b  = blockIdx.x >> 10;
  const int c0 = ct * 32;

  const float fy = y * (31.0f / 63.0f);
  const int y0 = (int)fy;
  const float wy = fy - (float)y0;
  const int y1 = min(y0 + 1, 31);

  // phase 1: xm tile, lane = x (coalesced 256B rows)
  {
    const int cb = (tid >> 6) * 8;
    const int xi = tid & 63;
#pragma unroll
    for (int j = 0; j < 8; ++j) {
      int c = cb + j;
      sm[c * 66 + xi] = xm[(((b << 9) + c0 + c) << 12) + (y << 6) + xi];
    }
  }
  // phase 2: xt rows y0,y1 (32 x-contiguous floats per (h,c) -> coalesced)
#pragma unroll
  for (int j = 0; j < 8; ++j) {
    int idx = j * 256 + tid;
    int xi = idx & 31, cc = (idx >> 5) & 31, h = idx >> 10;
    int yr = h ? y1 : y0;
    st[h * 1088 + cc * 34 + xi] =
        xt[(((b << 9) + c0 + cc) << 10) + (yr << 5) + xi];
  }
  __syncthreads();

  // phase 3: interpolate + fuse, write one c8 chunk per thread
  const float a = alpha[0];
  const int xo = tid & 63;
  const int cl = tid >> 6;             // local cchunk 0..3
  const float fx = xo * (31.0f / 63.0f);
  const int x0 = (int)fx;
  const float wx = fx - (float)x0;
  const int x1 = min(x0 + 1, 31);
  short8 ov;
#pragma unroll
  for (int j = 0; j < 8; ++j) {
    int c = cl * 8 + j;
    float t0 = st[c * 34 + x0], t1 = st[c * 34 + x1];
    float u0 = st[1088 + c * 34 + x0], u1 = st[1088 + c * 34 + x1];
    float top = t0 * (1.0f - wx) + t1 * wx;
    float bot = u0 * (1.0f - wx) + u1 * wx;
    float up = top * (1.0f - wy) + bot * wy;
    float val = up + a * sm[c * 66 + xo];
    ov[j] = (short)f2bf(val);
  }
  *(short8*)(Xp + ((c0 >> 3) + cl) * CPLANE +
             ((b * 66 + y + 1) * 66 + xo + 1) * 8) = ov;
}

// ---------------------------------------------------------------------------
// Repack weights OIHW fp32 -> [tap][cinchunk][cout][8] bf16 via LDS transpose.
// ---------------------------------------------------------------------------
template <int COUT>
__global__ __launch_bounds__(256) void prep_w_kernel(
    const float* __restrict__ w, unsigned short* __restrict__ Wg) {
  __shared__ unsigned short l[4608];   // [tap][cin]
  const int o = blockIdx.x, t = threadIdx.x;
  const float* src = w + o * 4608;
#pragma unroll
  for (int j = 0; j < 18; ++j) {
    int idx = j * 256 + t;             // = i*9 + tap
    l[(idx % 9) * 512 + idx / 9] = f2bf(src[idx]);
  }
  __syncthreads();
#pragma unroll
  for (int tap = 0; tap < 9; ++tap) {
    int cc = t >> 2;
    int off = ((tap * 64 + cc) * COUT + o) * 8 + ((2 * t) & 7);
    *(unsigned int*)(Wg + off) = *(const unsigned int*)(l + (tap << 9) + 2 * t);
  }
}

// ---------------------------------------------------------------------------
// Implicit-GEMM 3x3 conv + BN + ReLU.
// Input : c8 bf16 [64cc][8b][66][66][8] ; weights [9][64cc][COUT][8] bf16
// Block: 128 pixels x CTILE couts, 4 waves (2x2), wave = 64px x CTILE/2.
//
// Restructured vs previous version: B (weights) now goes DIRECTLY into
// registers (each wave reads a disjoint slice; LDS staging of B bought no
// sharing, only a per-tap barrier). A stays in LDS (9-tap reuse) and is
// DOUBLE-BUFFERED: stageA(cg+1) flies during cg's 9 taps. One __syncthreads
// per c-group (9/block) replaces 79 full vmcnt(0) barrier drains. B-fragment
// loads are software-prefetched one tap ahead; the compiler tracks them with
// counted vmcnt so they stay in flight across the whole tap body.
// A kc-stride padded 2112->2128 shorts so kc lane-groups hit banks
// {0,8,16,24} instead of all aliasing (GLD dests stay 16B-aligned).
// ---------------------------------------------------------------------------
template <int COUT, int CTILE, bool FINAL>
__global__ __launch_bounds__(256, 2) void conv3x3_kernel(
    const unsigned short* __restrict__ Xp, const unsigned short* __restrict__ Wg,
    const float* __restrict__ gamma, const float* __restrict__ beta,
    const float* __restrict__ mean, const float* __restrict__ var,
    unsigned short* __restrict__ OutPad, float* __restrict__ OutF) {
  constexpr int NCT = COUT / CTILE;
  constexpr int NI  = CTILE / 32;          // n-subtiles per wave
  constexpr int KCS = 2128;                // kc stride (4*528 + 16 pad) shorts
  constexpr int ABUF = 8 * KCS;            // 17024 shorts = 33.25 KiB
  __shared__ __align__(64) unsigned short Abuf[2][ABUF];   // double-buffered A

  const int tid = threadIdx.x;
  const int ptile = (int)blockIdx.x / NCT;
  const int ctile = (int)blockIdx.x % NCT;
  const int p0 = ptile * 128;          // 2 consecutive y-rows of one batch
  const int w = tid >> 6;
  const int lane = tid & 63;

  const int pb = p0 >> 12;             // batch
  const int yb = (p0 >> 6) & 63;       // first input padded row (dy=-1)
  const int arowg = ((pb * 66 + yb) * 66) * 8;   // global elem offset of row 0

  // ---- fragment read setup
  const int fi = lane & 15;
  const int kc = lane >> 4;
  const int wm = w >> 1, wn = w & 1;
  const int aLane = kc * KCS + (wm + 1) * 528 + (fi + 1) * 8;

  floatx4 acc[4][NI] = {};
  short8 bcur[2][NI], bnxt[2][NI];

  // ---- A staging: wave w owns kchunks {2w, 2w+1}; rows contiguous (528),
  // 16-short pad between kc blocks.
  auto stageA = [&](int cg, int bsel) {
#pragma unroll
    for (int kk = 0; kk < 2; ++kk) {
      const int kc2 = 2 * w + kk;
      const unsigned short* g = Xp + (cg * 8 + kc2) * CPLANE + arowg + lane * 8;
      unsigned short* d = &Abuf[bsel][0] + kc2 * KCS;
#pragma unroll
      for (int rr = 0; rr < 4; ++rr) {
        GLD(g + rr * 528,      d + rr * 528);        // x chunks 0..63
        GLD(g + rr * 528 + 16, d + rr * 528 + 16);   // x chunks 2..65 (overlap)
      }
    }
  };

  // ---- B fragments straight from global (L2-resident weights) to regs.
  // chunk = cg*8 + kc + 4t ; co = ctile*CTILE + wn*(CTILE/2) + ni*16 + fi
  auto loadB = [&](int tap, int cg, short8 (&dst)[2][NI]) {
    const unsigned short* base =
        Wg + ((tap * 64 + cg * 8 + kc) * COUT +
              ctile * CTILE + wn * (CTILE / 2) + fi) * 8;
#pragma unroll
    for (int t = 0; t < 2; ++t)
#pragma unroll
      for (int ni = 0; ni < NI; ++ni)
        dst[t][ni] = *(const short8*)(base + (t * 4 * COUT + ni * 16) * 8);
  };

  auto compute = [&](int bsel, int dy, int dx) {
    const unsigned short* ab = &Abuf[bsel][0] + aLane + dy * 528 + dx * 8;
#pragma unroll
    for (int t = 0; t < 2; ++t) {
      short8 af[4];
#pragma unroll
      for (int mi = 0; mi < 4; ++mi)
        af[mi] = *(const short8*)(ab + t * (4 * KCS) + mi * 128);
#pragma unroll
      for (int mi = 0; mi < 4; ++mi)
#pragma unroll
        for (int ni = 0; ni < NI; ++ni)
          acc[mi][ni] = __builtin_amdgcn_mfma_f32_16x16x32_bf16(
              af[mi], bcur[t][ni], acc[mi][ni], 0, 0, 0);
    }
  };

  // ---- main loop: one barrier per c-group.
  stageA(0, 0);
  loadB(0, 0, bcur);
  __syncthreads();                      // drains stageA(0) + prologue B loads

  int cur = 0;
  for (int cg = 0; cg < 8; ++cg) {
    if (cg < 7) stageA(cg + 1, cur ^ 1);   // flies during the 9 taps below
#pragma unroll
    for (int tap = 0; tap < 9; ++tap) {
      if (tap < 8)      loadB(tap + 1, cg, bnxt);      // prefetch next tap
      else if (cg < 7)  loadB(0, cg + 1, bnxt);        // prefetch next c-group
      compute(cur, tap / 3 - 1, tap % 3 - 1);
#pragma unroll
      for (int t = 0; t < 2; ++t)
#pragma unroll
        for (int ni = 0; ni < NI; ++ni) bcur[t][ni] = bnxt[t][ni];
    }
    __syncthreads();   // A(cg) reads done everywhere; A(cg+1) DMA drained
    cur ^= 1;
  }

  // ---- epilogue: BN + ReLU
  // C/D layout: col = lane&15 (=cout), row = (lane>>4)*4 + reg (=pixel)
#pragma unroll
  for (int ni = 0; ni < NI; ++ni) {
    const int co = ctile * CTILE + wn * (CTILE / 2) + ni * 16 + fi;
    const float sc = gamma[co] / sqrtf(var[co] + EPSV);
    const float sh2 = beta[co] - mean[co] * sc;
#pragma unroll
    for (int mi = 0; mi < 4; ++mi) {
      const int p = p0 + wm * 64 + mi * 16 + kc * 4;  // 4 consecutive pixels
      const int pbb = p >> 12;
      const int prem = p & 4095;
      if constexpr (FINAL) {
        floatx4 o;
#pragma unroll
        for (int r = 0; r < 4; ++r) o[r] = fmaxf(acc[mi][ni][r] * sc + sh2, 0.0f);
        *(floatx4*)(OutF + ((pbb * COUT + co) << 12) + prem) = o;  // NCHW fp32
      } else {
        const int py = prem >> 6, px = prem & 63;
        unsigned short* dst = OutPad + (co >> 3) * CPLANE +
            ((pbb * 66 + py + 1) * 66 + px + 1) * 8 + (co & 7);
#pragma unroll
        for (int r = 0; r < 4; ++r)
          dst[r * 8] = f2bf(fmaxf(acc[mi][ni][r] * sc + sh2, 0.0f));
      }
    }
  }
}

// ---------------------------------------------------------------------------
// workspace layout (bytes):
//   Xp0 : 0          .. 35684352   (64cc * 8*66*66 * 8 bf16)
//   Xp1 : 35684352   .. 71368704
//   Wg0 : 71368704   .. 76087296   (9*64*512*8 bf16)
//   Wg1 : 76087296   .. 78446592   (9*64*256*8 bf16)
// ---------------------------------------------------------------------------
extern "C" void kernel_launch(void* const* d_in, const int* in_sizes, int n_in,
                              void* d_out, int out_size, void* d_ws, size_t ws_size,
                              hipStream_t stream) {
  const float* xt    = (const float*)d_in[0];
  const float* xm    = (const float*)d_in[1];
  const float* alpha = (const float*)d_in[3];
  const float* w0    = (const float*)d_in[4];
  const float* g0    = (const float*)d_in[5];
  const float* b0    = (const float*)d_in[6];
  const float* m0    = (const float*)d_in[7];
  const float* v0    = (const float*)d_in[8];
  const float* w1    = (const float*)d_in[9];
  const float* g1    = (const float*)d_in[10];
  const float* b1    = (const float*)d_in[11];
  const float* m1    = (const float*)d_in[12];
  const float* v1    = (const float*)d_in[13];
  float* out = (float*)d_out;

  char* ws = (char*)d_ws;
  unsigned short* Xp0 = (unsigned short*)(ws);
  unsigned short* Xp1 = (unsigned short*)(ws + 35684352);
  unsigned short* Wg0 = (unsigned short*)(ws + 2 * 35684352);
  unsigned short* Wg1 = (unsigned short*)(ws + 2 * 35684352 + 4718592);

  border_zero_kernel<<<520, 256, 0, stream>>>(Xp0, Xp1);
  prep_w_kernel<512><<<512, 256, 0, stream>>>(w0, Wg0);
  prep_w_kernel<256><<<256, 256, 0, stream>>>(w1, Wg1);
  fuse_upsample_kernel<<<8192, 256, 0, stream>>>(xt, xm, alpha, Xp0);
  conv3x3_kernel<512, 128, false><<<1024, 256, 0, stream>>>(Xp0, Wg0, g0, b0, m0, v0, Xp1, nullptr);
  conv3x3_kernel<256, 64, true><<<1024, 256, 0, stream>>>(Xp1, Wg1, g1, b1, m1, v1, nullptr, out);
}

// Round 2
// 504.929 us; speedup vs baseline: 1.0782x; 1.0782x over previous
//
#include <hip/hip_runtime.h>
#include <stdint.h>

#define EPSV 1e-5f

// c8-chunked activation layout: elem = cc*278784 + ((b*66+y)*66+x)*8 + (c&7)
#define CPLANE 278784   // 8*66*66*8 elems per channel-chunk plane

using floatx4 = __attribute__((ext_vector_type(4))) float;
using short8  = __attribute__((ext_vector_type(8))) short;

// async global->LDS 16B DMA: data lands at ldsbase + lane*16
#define GLD(gp, lp) __builtin_amdgcn_global_load_lds( \
    (const __attribute__((address_space(1))) void*)(gp), \
    (__attribute__((address_space(3))) void*)(lp), 16, 0, 0)

__device__ __forceinline__ unsigned short f2bf(float f) {
  union { float f; unsigned int u; } x; x.f = f;
  unsigned int r = x.u + 0x7fffu + ((x.u >> 16) & 1u);  // RNE
  return (unsigned short)(r >> 16);
}

// ---------------------------------------------------------------------------
// Zero the halo border of both padded c8 buffers (2.13 MB each).
// ---------------------------------------------------------------------------
__global__ __launch_bounds__(256) void border_zero_kernel(
    unsigned short* __restrict__ Xp0, unsigned short* __restrict__ Xp1) {
  int idx = blockIdx.x * 256 + threadIdx.x;   // 520*256 = 133120 = 8*64*260
  int k = idx % 260;
  int rest = idx / 260;
  int cc = rest & 63;
  int b = rest >> 6;
  int py, px;
  if (k < 66)       { py = 0;  px = k; }
  else if (k < 132) { py = 65; px = k - 66; }
  else { int k2 = k - 132; py = 1 + (k2 >> 1); px = (k2 & 1) ? 65 : 0; }
  int off = cc * CPLANE + ((b * 66 + py) * 66 + px) * 8;
  short8 z = {};
  *(short8*)(Xp0 + off) = z;
  *(short8*)(Xp1 + off) = z;
}

// ---------------------------------------------------------------------------
// Upsample (align-corners bilinear 32->64) + alpha*xm fuse -> bf16 c8 layout.
// ---------------------------------------------------------------------------
__global__ __launch_bounds__(256) void fuse_upsample_kernel(
    const float* __restrict__ xt, const float* __restrict__ xm,
    const float* __restrict__ alpha, unsigned short* __restrict__ Xp) {
  __shared__ float sm[32 * 66];        // xm tile [c][x], pad 66
  __shared__ float st[2 * 32 * 34];    // xt rows [h][c][x0..31], pad 34

  const int tid = threadIdx.x;
  const int ct = blockIdx.x & 15;          // channel tile (32 ch)
  const int y  = (blockIdx.x >> 4) & 63;
  const int b  = blockIdx.x >> 10;
  const int c0 = ct * 32;

  const float fy = y * (31.0f / 63.0f);
  const int y0 = (int)fy;
  const float wy = fy - (float)y0;
  const int y1 = min(y0 + 1, 31);

  // phase 1: xm tile, lane = x (coalesced 256B rows)
  {
    const int cb = (tid >> 6) * 8;
    const int xi = tid & 63;
#pragma unroll
    for (int j = 0; j < 8; ++j) {
      int c = cb + j;
      sm[c * 66 + xi] = xm[(((b << 9) + c0 + c) << 12) + (y << 6) + xi];
    }
  }
  // phase 2: xt rows y0,y1 (32 x-contiguous floats per (h,c) -> coalesced)
#pragma unroll
  for (int j = 0; j < 8; ++j) {
    int idx = j * 256 + tid;
    int xi = idx & 31, cc = (idx >> 5) & 31, h = idx >> 10;
    int yr = h ? y1 : y0;
    st[h * 1088 + cc * 34 + xi] =
        xt[(((b << 9) + c0 + cc) << 10) + (yr << 5) + xi];
  }
  __syncthreads();

  // phase 3: interpolate + fuse, write one c8 chunk per thread
  const float a = alpha[0];
  const int xo = tid & 63;
  const int cl = tid >> 6;             // local cchunk 0..3
  const float fx = xo * (31.0f / 63.0f);
  const int x0 = (int)fx;
  const float wx = fx - (float)x0;
  const int x1 = min(x0 + 1, 31);
  short8 ov;
#pragma unroll
  for (int j = 0; j < 8; ++j) {
    int c = cl * 8 + j;
    float t0 = st[c * 34 + x0], t1 = st[c * 34 + x1];
    float u0 = st[1088 + c * 34 + x0], u1 = st[1088 + c * 34 + x1];
    float top = t0 * (1.0f - wx) + t1 * wx;
    float bot = u0 * (1.0f - wx) + u1 * wx;
    float up = top * (1.0f - wy) + bot * wy;
    float val = up + a * sm[c * 66 + xo];
    ov[j] = (short)f2bf(val);
  }
  *(short8*)(Xp + ((c0 >> 3) + cl) * CPLANE +
             ((b * 66 + y + 1) * 66 + xo + 1) * 8) = ov;
}

// ---------------------------------------------------------------------------
// Repack weights OIHW fp32 -> [tap][cinchunk][cout][8] bf16 via LDS transpose.
// ---------------------------------------------------------------------------
template <int COUT>
__global__ __launch_bounds__(256) void prep_w_kernel(
    const float* __restrict__ w, unsigned short* __restrict__ Wg) {
  __shared__ unsigned short l[4608];   // [tap][cin]
  const int o = blockIdx.x, t = threadIdx.x;
  const float* src = w + o * 4608;
#pragma unroll
  for (int j = 0; j < 18; ++j) {
    int idx = j * 256 + t;             // = i*9 + tap
    l[(idx % 9) * 512 + idx / 9] = f2bf(src[idx]);
  }
  __syncthreads();
#pragma unroll
  for (int tap = 0; tap < 9; ++tap) {
    int cc = t >> 2;
    int off = ((tap * 64 + cc) * COUT + o) * 8 + ((2 * t) & 7);
    *(unsigned int*)(Wg + off) = *(const unsigned int*)(l + (tap << 9) + 2 * t);
  }
}

// ---------------------------------------------------------------------------
// Implicit-GEMM 3x3 conv + BN + ReLU.
// Input : c8 bf16 [64cc][8b][66][66][8] ; weights [9][64cc][COUT][8] bf16
// Block: 128 pixels x CTILE couts, 4 waves (2x2), wave = 64px x CTILE/2.
//
// B (weights) goes straight global->registers (each wave reads a disjoint
// slice; L2-resident after first touch), PING-PONGED between two register
// sets selected by STATIC tap parity (tap loop fully unrolled; 9 is odd so
// parity flips per c-group -> cg loop unrolled in pairs). No register
// copies, no vmcnt(0) drain per tap: the only wait is the counted vmcnt
// the compiler emits before the NEXT tap's MFMAs, issued a full tap
// (~300 cyc wall) earlier. A stays in LDS (9-tap reuse), double-buffered,
// one __syncthreads per c-group (9 total per block, was 79 drains).
// ---------------------------------------------------------------------------
template <int COUT, int CTILE, bool FINAL>
__global__ __launch_bounds__(256, 2) void conv3x3_kernel(
    const unsigned short* __restrict__ Xp, const unsigned short* __restrict__ Wg,
    const float* __restrict__ gamma, const float* __restrict__ beta,
    const float* __restrict__ mean, const float* __restrict__ var,
    unsigned short* __restrict__ OutPad, float* __restrict__ OutF) {
  constexpr int NCT = COUT / CTILE;
  constexpr int NI  = CTILE / 32;          // n-subtiles per wave
  constexpr int KCS = 2128;                // kc stride (4*528 + 16 pad) shorts
  constexpr int ABUF = 8 * KCS;            // 17024 shorts = 33.25 KiB
  __shared__ __align__(64) unsigned short Abuf[2][ABUF];   // double-buffered A

  const int tid = threadIdx.x;
  const int ptile = (int)blockIdx.x / NCT;
  const int ctile = (int)blockIdx.x % NCT;
  const int p0 = ptile * 128;          // 2 consecutive y-rows of one batch
  const int w = tid >> 6;
  const int lane = tid & 63;

  const int pb = p0 >> 12;             // batch
  const int yb = (p0 >> 6) & 63;       // first input padded row (dy=-1)
  const int arowg = ((pb * 66 + yb) * 66) * 8;   // global elem offset of row 0

  // ---- fragment read setup
  const int fi = lane & 15;
  const int kc = lane >> 4;
  const int wm = w >> 1, wn = w & 1;
  const int aLane = kc * KCS + (wm + 1) * 528 + (fi + 1) * 8;

  floatx4 acc[4][NI] = {};
  short8 B0[2][NI], B1[2][NI];         // ping-pong B fragment sets

  int cur = 0;                         // A buffer selector

  // ---- A staging: wave w owns kchunks {2w, 2w+1}; rows contiguous (528).
  auto stageA = [&](int cg, int bsel) {
#pragma unroll
    for (int kk = 0; kk < 2; ++kk) {
      const int kc2 = 2 * w + kk;
      const unsigned short* g = Xp + (cg * 8 + kc2) * CPLANE + arowg + lane * 8;
      unsigned short* d = &Abuf[bsel][0] + kc2 * KCS;
#pragma unroll
      for (int rr = 0; rr < 4; ++rr) {
        GLD(g + rr * 528,      d + rr * 528);        // x chunks 0..63
        GLD(g + rr * 528 + 16, d + rr * 528 + 16);   // x chunks 2..65 (overlap)
      }
    }
  };

  // ---- B fragments straight from global (L2-resident weights) to regs.
  // chunk = cg*8 + kc + 4t ; co = ctile*CTILE + wn*(CTILE/2) + ni*16 + fi
  auto loadB = [&](int tap, int cg, short8 (&dst)[2][NI]) {
    const unsigned short* base =
        Wg + ((tap * 64 + cg * 8 + kc) * COUT +
              ctile * CTILE + wn * (CTILE / 2) + fi) * 8;
#pragma unroll
    for (int t = 0; t < 2; ++t)
#pragma unroll
      for (int ni = 0; ni < NI; ++ni)
        dst[t][ni] = *(const short8*)(base + (t * 4 * COUT + ni * 16) * 8);
  };

  // ---- one tap: prefetch next tap's B into bn, compute with bc.
  auto tapStep = [&](int cg, int tap, short8 (&bc)[2][NI],
                     short8 (&bn)[2][NI]) {
    if (tap < 8)      loadB(tap + 1, cg, bn);        // prefetch next tap
    else if (cg < 7)  loadB(0, cg + 1, bn);          // prefetch next c-group
    const int dy = tap / 3 - 1, dx = tap % 3 - 1;
    const unsigned short* ab = &Abuf[cur][0] + aLane + dy * 528 + dx * 8;
#pragma unroll
    for (int t = 0; t < 2; ++t) {
      short8 af[4];
#pragma unroll
      for (int mi = 0; mi < 4; ++mi)
        af[mi] = *(const short8*)(ab + t * (4 * KCS) + mi * 128);
#pragma unroll
      for (int mi = 0; mi < 4; ++mi)
#pragma unroll
        for (int ni = 0; ni < NI; ++ni)
          acc[mi][ni] = __builtin_amdgcn_mfma_f32_16x16x32_bf16(
              af[mi], bc[t][ni], acc[mi][ni], 0, 0, 0);
    }
  };

  // ---- main loop: cg pairs keep tap parity static (9 taps = odd).
  stageA(0, 0);
  loadB(0, 0, B0);
  __syncthreads();                      // drains stageA(0); B0 waited by use

  for (int cgp = 0; cgp < 4; ++cgp) {
    const int cg = 2 * cgp;
    stageA(cg + 1, cur ^ 1);            // flies during the 9 taps below
#pragma unroll
    for (int tap = 0; tap < 9; ++tap) {
      if ((tap & 1) == 0) tapStep(cg, tap, B0, B1);
      else                tapStep(cg, tap, B1, B0);
    }
    __syncthreads();                    // A(cg) reads done; A(cg+1) landed
    cur ^= 1;
    if (cg + 2 < 8) stageA(cg + 2, cur ^ 1);
#pragma unroll
    for (int tap = 0; tap < 9; ++tap) { // parity-swapped roles (9 odd)
      if ((tap & 1) == 0) tapStep(cg + 1, tap, B1, B0);
      else                tapStep(cg + 1, tap, B0, B1);
    }
    __syncthreads();
    cur ^= 1;
  }

  // ---- epilogue: BN + ReLU
  // C/D layout: col = lane&15 (=cout), row = (lane>>4)*4 + reg (=pixel)
#pragma unroll
  for (int ni = 0; ni < NI; ++ni) {
    const int co = ctile * CTILE + wn * (CTILE / 2) + ni * 16 + fi;
    const float sc = gamma[co] / sqrtf(var[co] + EPSV);
    const float sh2 = beta[co] - mean[co] * sc;
#pragma unroll
    for (int mi = 0; mi < 4; ++mi) {
      const int p = p0 + wm * 64 + mi * 16 + kc * 4;  // 4 consecutive pixels
      const int pbb = p >> 12;
      const int prem = p & 4095;
      if constexpr (FINAL) {
        floatx4 o;
#pragma unroll
        for (int r = 0; r < 4; ++r) o[r] = fmaxf(acc[mi][ni][r] * sc + sh2, 0.0f);
        *(floatx4*)(OutF + ((pbb * COUT + co) << 12) + prem) = o;  // NCHW fp32
      } else {
        const int py = prem >> 6, px = prem & 63;
        unsigned short* dst = OutPad + (co >> 3) * CPLANE +
            ((pbb * 66 + py + 1) * 66 + px + 1) * 8 + (co & 7);
#pragma unroll
        for (int r = 0; r < 4; ++r)
          dst[r * 8] = f2bf(fmaxf(acc[mi][ni][r] * sc + sh2, 0.0f));
      }
    }
  }
}

// ---------------------------------------------------------------------------
// workspace layout (bytes):
//   Xp0 : 0          .. 35684352   (64cc * 8*66*66 * 8 bf16)
//   Xp1 : 35684352   .. 71368704
//   Wg0 : 71368704   .. 76087296   (9*64*512*8 bf16)
//   Wg1 : 76087296   .. 78446592   (9*64*256*8 bf16)
// ---------------------------------------------------------------------------
extern "C" void kernel_launch(void* const* d_in, const int* in_sizes, int n_in,
                              void* d_out, int out_size, void* d_ws, size_t ws_size,
                              hipStream_t stream) {
  const float* xt    = (const float*)d_in[0];
  const float* xm    = (const float*)d_in[1];
  const float* alpha = (const float*)d_in[3];
  const float* w0    = (const float*)d_in[4];
  const float* g0    = (const float*)d_in[5];
  const float* b0    = (const float*)d_in[6];
  const float* m0    = (const float*)d_in[7];
  const float* v0    = (const float*)d_in[8];
  const float* w1    = (const float*)d_in[9];
  const float* g1    = (const float*)d_in[10];
  const float* b1    = (const float*)d_in[11];
  const float* m1    = (const float*)d_in[12];
  const float* v1    = (const float*)d_in[13];
  float* out = (float*)d_out;

  char* ws = (char*)d_ws;
  unsigned short* Xp0 = (unsigned short*)(ws);
  unsigned short* Xp1 = (unsigned short*)(ws + 35684352);
  unsigned short* Wg0 = (unsigned short*)(ws + 2 * 35684352);
  unsigned short* Wg1 = (unsigned short*)(ws + 2 * 35684352 + 4718592);

  border_zero_kernel<<<520, 256, 0, stream>>>(Xp0, Xp1);
  prep_w_kernel<512><<<512, 256, 0, stream>>>(w0, Wg0);
  prep_w_kernel<256><<<256, 256, 0, stream>>>(w1, Wg1);
  fuse_upsample_kernel<<<8192, 256, 0, stream>>>(xt, xm, alpha, Xp0);
  conv3x3_kernel<512, 128, false><<<1024, 256, 0, stream>>>(Xp0, Wg0, g0, b0, m0, v0, Xp1, nullptr);
  conv3x3_kernel<256, 128, true><<<512, 256, 0, stream>>>(Xp1, Wg1, g1, b1, m1, v1, nullptr, out);
}

// Round 6
// 461.534 us; speedup vs baseline: 1.1795x; 1.0940x over previous
//
#include <hip/hip_runtime.h>
#include <stdint.h>

#define EPSV 1e-5f

// c8-chunked activation layout: elem = cc*278784 + ((b*66+y)*66+x)*8 + (c&7)
#define CPLANE 278784   // 8*66*66*8 elems per channel-chunk plane

using floatx4 = __attribute__((ext_vector_type(4))) float;
using short8  = __attribute__((ext_vector_type(8))) short;

// async global->LDS 16B DMA: data lands at ldsbase + lane*16
#define GLD(gp, lp) __builtin_amdgcn_global_load_lds( \
    (const __attribute__((address_space(1))) void*)(gp), \
    (__attribute__((address_space(3))) void*)(lp), 16, 0, 0)

__device__ __forceinline__ unsigned short f2bf(float f) {
  union { float f; unsigned int u; } x; x.f = f;
  unsigned int r = x.u + 0x7fffu + ((x.u >> 16) & 1u);  // RNE
  return (unsigned short)(r >> 16);
}

// ---------------------------------------------------------------------------
// Zero the halo border of both padded c8 buffers (2.13 MB each).
// ---------------------------------------------------------------------------
__global__ __launch_bounds__(256) void border_zero_kernel(
    unsigned short* __restrict__ Xp0, unsigned short* __restrict__ Xp1) {
  int idx = blockIdx.x * 256 + threadIdx.x;   // 520*256 = 133120 = 8*64*260
  int k = idx % 260;
  int rest = idx / 260;
  int cc = rest & 63;
  int b = rest >> 6;
  int py, px;
  if (k < 66)       { py = 0;  px = k; }
  else if (k < 132) { py = 65; px = k - 66; }
  else { int k2 = k - 132; py = 1 + (k2 >> 1); px = (k2 & 1) ? 65 : 0; }
  int off = cc * CPLANE + ((b * 66 + py) * 66 + px) * 8;
  short8 z = {};
  *(short8*)(Xp0 + off) = z;
  *(short8*)(Xp1 + off) = z;
}

// ---------------------------------------------------------------------------
// Upsample (align-corners bilinear 32->64) + alpha*xm fuse -> bf16 c8 layout.
// ---------------------------------------------------------------------------
__global__ __launch_bounds__(256) void fuse_upsample_kernel(
    const float* __restrict__ xt, const float* __restrict__ xm,
    const float* __restrict__ alpha, unsigned short* __restrict__ Xp) {
  __shared__ float sm[32 * 66];        // xm tile [c][x], pad 66
  __shared__ float st[2 * 32 * 34];    // xt rows [h][c][x0..31], pad 34

  const int tid = threadIdx.x;
  const int ct = blockIdx.x & 15;          // channel tile (32 ch)
  const int y  = (blockIdx.x >> 4) & 63;
  const int b  = blockIdx.x >> 10;
  const int c0 = ct * 32;

  const float fy = y * (31.0f / 63.0f);
  const int y0 = (int)fy;
  const float wy = fy - (float)y0;
  const int y1 = min(y0 + 1, 31);

  // phase 1: xm tile, lane = x (coalesced 256B rows)
  {
    const int cb = (tid >> 6) * 8;
    const int xi = tid & 63;
#pragma unroll
    for (int j = 0; j < 8; ++j) {
      int c = cb + j;
      sm[c * 66 + xi] = xm[(((b << 9) + c0 + c) << 12) + (y << 6) + xi];
    }
  }
  // phase 2: xt rows y0,y1 (32 x-contiguous floats per (h,c) -> coalesced)
#pragma unroll
  for (int j = 0; j < 8; ++j) {
    int idx = j * 256 + tid;
    int xi = idx & 31, cc = (idx >> 5) & 31, h = idx >> 10;
    int yr = h ? y1 : y0;
    st[h * 1088 + cc * 34 + xi] =
        xt[(((b << 9) + c0 + cc) << 10) + (yr << 5) + xi];
  }
  __syncthreads();

  // phase 3: interpolate + fuse, write one c8 chunk per thread
  const float a = alpha[0];
  const int xo = tid & 63;
  const int cl = tid >> 6;             // local cchunk 0..3
  const float fx = xo * (31.0f / 63.0f);
  const int x0 = (int)fx;
  const float wx = fx - (float)x0;
  const int x1 = min(x0 + 1, 31);
  short8 ov;
#pragma unroll
  for (int j = 0; j < 8; ++j) {
    int c = cl * 8 + j;
    float t0 = st[c * 34 + x0], t1 = st[c * 34 + x1];
    float u0 = st[1088 + c * 34 + x0], u1 = st[1088 + c * 34 + x1];
    float top = t0 * (1.0f - wx) + t1 * wx;
    float bot = u0 * (1.0f - wx) + u1 * wx;
    float up = top * (1.0f - wy) + bot * wy;
    float val = up + a * sm[c * 66 + xo];
    ov[j] = (short)f2bf(val);
  }
  *(short8*)(Xp + ((c0 >> 3) + cl) * CPLANE +
             ((b * 66 + y + 1) * 66 + xo + 1) * 8) = ov;
}

// ---------------------------------------------------------------------------
// Repack weights OIHW fp32 -> [tap][cinchunk][cout][8] bf16 via LDS transpose.
// ---------------------------------------------------------------------------
template <int COUT>
__global__ __launch_bounds__(256) void prep_w_kernel(
    const float* __restrict__ w, unsigned short* __restrict__ Wg) {
  __shared__ unsigned short l[4608];   // [tap][cin]
  const int o = blockIdx.x, t = threadIdx.x;
  const float* src = w + o * 4608;
#pragma unroll
  for (int j = 0; j < 18; ++j) {
    int idx = j * 256 + t;             // = i*9 + tap
    l[(idx % 9) * 512 + idx / 9] = f2bf(src[idx]);
  }
  __syncthreads();
#pragma unroll
  for (int tap = 0; tap < 9; ++tap) {
    int cc = t >> 2;
    int off = ((tap * 64 + cc) * COUT + o) * 8 + ((2 * t) & 7);
    *(unsigned int*)(Wg + off) = *(const unsigned int*)(l + (tap << 9) + 2 * t);
  }
}

// ---------------------------------------------------------------------------
// Implicit-GEMM 3x3 conv + BN + ReLU, A-resident / B-prefetch K-loop.
// Input : c8 bf16 [64cc][8b][66][66][8] ; weights [9][64cc][COUT][8] bf16
// Block: 128 pixels x CTILE couts, 4 waves (2x2), wave = 64px x CTILE/2.
//
// XCD-aware CTILE-MAJOR block swizzle (compile-time grid = 256*NCT):
// with default blockIdx order, consecutive blocks (round-robined over the
// 8 XCDs) use different weight slices, so each XCD's 4 MiB L2 cycles
// through the whole weight array once per ptile (rocprof: 150 MB FETCH vs
// ~40 MB ideal; B loads at L3/HBM latency stall every tap's drain
// barrier). Bijective remap: each XCD owns ONE ctile slice (1.18 MB ->
// L2-resident) and adjacent ptiles (A halo overlap). NWG % 8 == 0 always.
// ---------------------------------------------------------------------------
template <int COUT, int CTILE, bool FINAL>
__global__ __launch_bounds__(256) void conv3x3_kernel(
    const unsigned short* __restrict__ Xp, const unsigned short* __restrict__ Wg,
    const float* __restrict__ gamma, const float* __restrict__ beta,
    const float* __restrict__ mean, const float* __restrict__ var,
    unsigned short* __restrict__ OutPad, float* __restrict__ OutF) {
  constexpr int NCT = COUT / CTILE;
  constexpr int NI  = CTILE / 32;          // n-subtiles per wave
  constexpr int NWG = 256 * NCT;           // launched grid size (exact)
  constexpr int QXC = NWG / 8;             // blocks per XCD
  __shared__ unsigned short Abuf[16896];   // [kc 8][row 4][x 66][8] = 33 KiB
  __shared__ unsigned short Bbuf0[CTILE * 64];  // [kc 8][CTILE][8]
  __shared__ unsigned short Bbuf1[CTILE * 64];

  const int tid = threadIdx.x;
  // ---- XCD swizzle: xcd = bid%8 gets logical chunk [xcd*QXC, (xcd+1)*QXC).
  // Logical order is ctile-major so each XCD sees exactly one ctile.
  const int bid = (int)blockIdx.x;
  const int logical = (bid & 7) * QXC + (bid >> 3);
  const int ptile = logical & 255;         // 256 ptiles (32768 px / 128)
  const int ctile = logical >> 8;
  const int p0 = ptile * 128;          // 2 consecutive y-rows of one batch
  const int w = tid >> 6;
  const int lane = tid & 63;

  const int pb = p0 >> 12;             // batch
  const int yb = (p0 >> 6) & 63;       // first input padded row (dy=-1)
  const int arowg = ((pb * 66 + yb) * 66) * 8;   // global elem offset of row 0

  // ---- fragment read setup
  const int fi = lane & 15;
  const int kc = lane >> 4;
  const int wm = w >> 1, wn = w & 1;
  const int aLane = kc * 2112 + (wm + 1) * 528 + (fi + 1) * 8;
  const int bLane = kc * CTILE * 8 + (wn * (CTILE / 2) + fi) * 8;

  floatx4 acc[4][NI] = {};

  // ---- staging lambdas (wave w owns kchunks {2w, 2w+1})
  auto stageA = [&](int cg) {
#pragma unroll
    for (int kk = 0; kk < 2; ++kk) {
      const int kc2 = 2 * w + kk;
      const unsigned short* g = Xp + (cg * 8 + kc2) * CPLANE + arowg + lane * 8;
      unsigned short* d = Abuf + kc2 * 2112;
#pragma unroll
      for (int rr = 0; rr < 4; ++rr) {
        GLD(g + rr * 528,      d + rr * 528);        // x chunks 0..63
        GLD(g + rr * 528 + 16, d + rr * 528 + 16);   // x chunks 2..65 (overlap)
      }
    }
  };
  auto stageB = [&](int tap, int cg, unsigned short* dst) {
#pragma unroll
    for (int kk = 0; kk < 2; ++kk) {
      const int kc2 = 2 * w + kk;
      const unsigned short* g =
          Wg + ((tap * 64 + cg * 8 + kc2) * COUT + ctile * CTILE + lane) * 8;
#pragma unroll
      for (int half = 0; half < CTILE / 64; ++half)
        GLD(g + half * 64 * 8, dst + (kc2 * CTILE + half * 64) * 8);
    }
  };
  auto compute = [&](const unsigned short* Bsel, int dy, int dx) {
#pragma unroll
    for (int t = 0; t < 2; ++t) {
      short8 af[4];
#pragma unroll
      for (int mi = 0; mi < 4; ++mi)
        af[mi] = *(const short8*)(Abuf + aLane + t * 8448 + dy * 528 +
                                  (mi * 16 + dx) * 8);
      short8 bfr[NI];
#pragma unroll
      for (int ni = 0; ni < NI; ++ni)
        bfr[ni] = *(const short8*)(Bsel + bLane + t * CTILE * 32 + ni * 128);
#pragma unroll
      for (int mi = 0; mi < 4; ++mi)
#pragma unroll
        for (int ni = 0; ni < NI; ++ni)
          acc[mi][ni] = __builtin_amdgcn_mfma_f32_16x16x32_bf16(
              af[mi], bfr[ni], acc[mi][ni], 0, 0, 0);
    }
  };

  // ---- main loop
  int buf = 0;
  stageA(0);
  stageB(0, 0, Bbuf0);
  __syncthreads();
  for (int cg = 0; cg < 8; ++cg) {
#pragma unroll
    for (int tap = 0; tap < 9; ++tap) {
      unsigned short* cur = buf ? Bbuf1 : Bbuf0;
      unsigned short* nxt = buf ? Bbuf0 : Bbuf1;
      if (tap < 8)      stageB(tap + 1, cg, nxt);      // prefetch next tap
      else if (cg < 7)  stageB(0, cg + 1, nxt);        // prefetch next c-group
      compute(cur, tap / 3 - 1, tap % 3 - 1);
      __syncthreads();   // drains prefetch DMA (flew during MFMAs)
      buf ^= 1;
    }
    if (cg < 7) {
      stageA(cg + 1);    // A region free: all taps of cg done
      __syncthreads();
    }
  }

  // ---- epilogue: BN + ReLU
  // C/D layout: col = lane&15 (=cout), row = (lane>>4)*4 + reg (=pixel)
#pragma unroll
  for (int ni = 0; ni < NI; ++ni) {
    const int co = ctile * CTILE + wn * (CTILE / 2) + ni * 16 + fi;
    const float sc = gamma[co] / sqrtf(var[co] + EPSV);
    const float sh2 = beta[co] - mean[co] * sc;
#pragma unroll
    for (int mi = 0; mi < 4; ++mi) {
      const int p = p0 + wm * 64 + mi * 16 + kc * 4;  // 4 consecutive pixels
      const int pbb = p >> 12;
      const int prem = p & 4095;
      if constexpr (FINAL) {
        floatx4 o;
#pragma unroll
        for (int r = 0; r < 4; ++r) o[r] = fmaxf(acc[mi][ni][r] * sc + sh2, 0.0f);
        *(floatx4*)(OutF + ((pbb * COUT + co) << 12) + prem) = o;  // NCHW fp32
      } else {
        const int py = prem >> 6, px = prem & 63;
        unsigned short* dst = OutPad + (co >> 3) * CPLANE +
            ((pbb * 66 + py + 1) * 66 + px + 1) * 8 + (co & 7);
#pragma unroll
        for (int r = 0; r < 4; ++r)
          dst[r * 8] = f2bf(fmaxf(acc[mi][ni][r] * sc + sh2, 0.0f));
      }
    }
  }
}

// ---------------------------------------------------------------------------
// workspace layout (bytes):
//   Xp0 : 0          .. 35684352   (64cc * 8*66*66 * 8 bf16)
//   Xp1 : 35684352   .. 71368704
//   Wg0 : 71368704   .. 76087296   (9*64*512*8 bf16)
//   Wg1 : 76087296   .. 78446592   (9*64*256*8 bf16)
// ---------------------------------------------------------------------------
extern "C" void kernel_launch(void* const* d_in, const int* in_sizes, int n_in,
                              void* d_out, int out_size, void* d_ws, size_t ws_size,
                              hipStream_t stream) {
  const float* xt    = (const float*)d_in[0];
  const float* xm    = (const float*)d_in[1];
  const float* alpha = (const float*)d_in[3];
  const float* w0    = (const float*)d_in[4];
  const float* g0    = (const float*)d_in[5];
  const float* b0    = (const float*)d_in[6];
  const float* m0    = (const float*)d_in[7];
  const float* v0    = (const float*)d_in[8];
  const float* w1    = (const float*)d_in[9];
  const float* g1    = (const float*)d_in[10];
  const float* b1    = (const float*)d_in[11];
  const float* m1    = (const float*)d_in[12];
  const float* v1    = (const float*)d_in[13];
  float* out = (float*)d_out;

  char* ws = (char*)d_ws;
  unsigned short* Xp0 = (unsigned short*)(ws);
  unsigned short* Xp1 = (unsigned short*)(ws + 35684352);
  unsigned short* Wg0 = (unsigned short*)(ws + 2 * 35684352);
  unsigned short* Wg1 = (unsigned short*)(ws + 2 * 35684352 + 4718592);

  border_zero_kernel<<<520, 256, 0, stream>>>(Xp0, Xp1);
  prep_w_kernel<512><<<512, 256, 0, stream>>>(w0, Wg0);
  prep_w_kernel<256><<<256, 256, 0, stream>>>(w1, Wg1);
  fuse_upsample_kernel<<<8192, 256, 0, stream>>>(xt, xm, alpha, Xp0);
  conv3x3_kernel<512, 128, false><<<1024, 256, 0, stream>>>(Xp0, Wg0, g0, b0, m0, v0, Xp1, nullptr);
  conv3x3_kernel<256, 128, true><<<512, 256, 0, stream>>>(Xp1, Wg1, g1, b1, m1, v1, nullptr, out);
}

// Round 7
// 450.904 us; speedup vs baseline: 1.2073x; 1.0236x over previous
//
#include <hip/hip_runtime.h>
#include <stdint.h>

#define EPSV 1e-5f

// c8-chunked activation layout: elem = cc*278784 + ((b*66+y)*66+x)*8 + (c&7)
#define CPLANE 278784   // 8*66*66*8 elems per channel-chunk plane

using floatx4 = __attribute__((ext_vector_type(4))) float;
using short8  = __attribute__((ext_vector_type(8))) short;

// async global->LDS 16B DMA: data lands at ldsbase + lane*16
#define GLD(gp, lp) __builtin_amdgcn_global_load_lds( \
    (const __attribute__((address_space(1))) void*)(gp), \
    (__attribute__((address_space(3))) void*)(lp), 16, 0, 0)

__device__ __forceinline__ unsigned short f2bf(float f) {
  union { float f; unsigned int u; } x; x.f = f;
  unsigned int r = x.u + 0x7fffu + ((x.u >> 16) & 1u);  // RNE
  return (unsigned short)(r >> 16);
}

// ---------------------------------------------------------------------------
// Zero the halo border of both padded c8 buffers (2.13 MB each).
// ---------------------------------------------------------------------------
__global__ __launch_bounds__(256) void border_zero_kernel(
    unsigned short* __restrict__ Xp0, unsigned short* __restrict__ Xp1) {
  int idx = blockIdx.x * 256 + threadIdx.x;   // 520*256 = 133120 = 8*64*260
  int k = idx % 260;
  int rest = idx / 260;
  int cc = rest & 63;
  int b = rest >> 6;
  int py, px;
  if (k < 66)       { py = 0;  px = k; }
  else if (k < 132) { py = 65; px = k - 66; }
  else { int k2 = k - 132; py = 1 + (k2 >> 1); px = (k2 & 1) ? 65 : 0; }
  int off = cc * CPLANE + ((b * 66 + py) * 66 + px) * 8;
  short8 z = {};
  *(short8*)(Xp0 + off) = z;
  *(short8*)(Xp1 + off) = z;
}

// ---------------------------------------------------------------------------
// Upsample (align-corners bilinear 32->64) + alpha*xm fuse -> bf16 c8 layout.
// ---------------------------------------------------------------------------
__global__ __launch_bounds__(256) void fuse_upsample_kernel(
    const float* __restrict__ xt, const float* __restrict__ xm,
    const float* __restrict__ alpha, unsigned short* __restrict__ Xp) {
  __shared__ float sm[32 * 66];        // xm tile [c][x], pad 66
  __shared__ float st[2 * 32 * 34];    // xt rows [h][c][x0..31], pad 34

  const int tid = threadIdx.x;
  const int ct = blockIdx.x & 15;          // channel tile (32 ch)
  const int y  = (blockIdx.x >> 4) & 63;
  const int b  = blockIdx.x >> 10;
  const int c0 = ct * 32;

  const float fy = y * (31.0f / 63.0f);
  const int y0 = (int)fy;
  const float wy = fy - (float)y0;
  const int y1 = min(y0 + 1, 31);

  // phase 1: xm tile, lane = x (coalesced 256B rows)
  {
    const int cb = (tid >> 6) * 8;
    const int xi = tid & 63;
#pragma unroll
    for (int j = 0; j < 8; ++j) {
      int c = cb + j;
      sm[c * 66 + xi] = xm[(((b << 9) + c0 + c) << 12) + (y << 6) + xi];
    }
  }
  // phase 2: xt rows y0,y1 (32 x-contiguous floats per (h,c) -> coalesced)
#pragma unroll
  for (int j = 0; j < 8; ++j) {
    int idx = j * 256 + tid;
    int xi = idx & 31, cc = (idx >> 5) & 31, h = idx >> 10;
    int yr = h ? y1 : y0;
    st[h * 1088 + cc * 34 + xi] =
        xt[(((b << 9) + c0 + cc) << 10) + (yr << 5) + xi];
  }
  __syncthreads();

  // phase 3: interpolate + fuse, write one c8 chunk per thread
  const float a = alpha[0];
  const int xo = tid & 63;
  const int cl = tid >> 6;             // local cchunk 0..3
  const float fx = xo * (31.0f / 63.0f);
  const int x0 = (int)fx;
  const float wx = fx - (float)x0;
  const int x1 = min(x0 + 1, 31);
  short8 ov;
#pragma unroll
  for (int j = 0; j < 8; ++j) {
    int c = cl * 8 + j;
    float t0 = st[c * 34 + x0], t1 = st[c * 34 + x1];
    float u0 = st[1088 + c * 34 + x0], u1 = st[1088 + c * 34 + x1];
    float top = t0 * (1.0f - wx) + t1 * wx;
    float bot = u0 * (1.0f - wx) + u1 * wx;
    float up = top * (1.0f - wy) + bot * wy;
    float val = up + a * sm[c * 66 + xo];
    ov[j] = (short)f2bf(val);
  }
  *(short8*)(Xp + ((c0 >> 3) + cl) * CPLANE +
             ((b * 66 + y + 1) * 66 + xo + 1) * 8) = ov;
}

// ---------------------------------------------------------------------------
// Repack weights OIHW fp32 -> [tap][cinchunk][cout][8] bf16 via LDS transpose.
// ---------------------------------------------------------------------------
template <int COUT>
__global__ __launch_bounds__(256) void prep_w_kernel(
    const float* __restrict__ w, unsigned short* __restrict__ Wg) {
  __shared__ unsigned short l[4608];   // [tap][cin]
  const int o = blockIdx.x, t = threadIdx.x;
  const float* src = w + o * 4608;
#pragma unroll
  for (int j = 0; j < 18; ++j) {
    int idx = j * 256 + t;             // = i*9 + tap
    l[(idx % 9) * 512 + idx / 9] = f2bf(src[idx]);
  }
  __syncthreads();
#pragma unroll
  for (int tap = 0; tap < 9; ++tap) {
    int cc = t >> 2;
    int off = ((tap * 64 + cc) * COUT + o) * 8 + ((2 * t) & 7);
    *(unsigned int*)(Wg + off) = *(const unsigned int*)(l + (tap << 9) + 2 * t);
  }
}

// ---------------------------------------------------------------------------
// FAT-WAVE implicit-GEMM 3x3 conv + BN + ReLU (conv0).
// Rocprof showed conv0 LDS-BW-bound: wave tile 64x64 reads 16 KB LDS per
// 0.5 MFLOP tap (32 FLOP/B); LDS-port demand ~1.9k cyc/tap vs MFMA 1.2k.
// Fix: wave = 128px x 64cout (intensity 42.7 FLOP/B), block = 256px x
// 256cout, 8 waves (2x4), 512 threads, acc[8][4]=128 VGPR
// (launch_bounds(512,2) -> 256 VGPR budget, 2 waves/SIMD).
// MFMA/tap/CU = 512*4.85 = 2.5k cyc > LDS ~1.8k -> MFMA-bound.
// LDS 114 KB -> 1 block/CU; grid = 256 = exactly 1 block/CU.
// kc strides padded (+8 shorts) to stagger the 4 kc lane-group banks.
// Same proven schedule: per-tap B double-buffer + drain barrier; A staged
// once per c-group. Same ctile-major XCD swizzle (weights L2-resident).
// ---------------------------------------------------------------------------
template <int COUT, bool FINAL>
__global__ __launch_bounds__(512, 2) void conv3x3_fat_kernel(
    const unsigned short* __restrict__ Xp, const unsigned short* __restrict__ Wg,
    const float* __restrict__ gamma, const float* __restrict__ beta,
    const float* __restrict__ mean, const float* __restrict__ var,
    unsigned short* __restrict__ OutPad, float* __restrict__ OutF) {
  constexpr int NCT = COUT / 256;          // ctile count
  constexpr int NWG = 128 * NCT;           // 128 ptiles (256 px each)
  constexpr int QXC = NWG / 8;             // blocks per XCD
  constexpr int AKS = 3176;                // A kc stride shorts (6*528 + 8)
  constexpr int BKS = 2056;                // B kc stride shorts (256*8 + 8)
  __shared__ unsigned short Abuf[8 * AKS];     // 50816 B: [kc][6 rows][528]
  __shared__ unsigned short Bbuf0[8 * BKS];    // 32896 B: [kc][256][8]
  __shared__ unsigned short Bbuf1[8 * BKS];    // total 116608 B

  const int tid = threadIdx.x;
  const int w = tid >> 6;              // wave 0..7
  const int lane = tid & 63;
  const int wm = w >> 2;               // 0..1 : 128-px half (2 out rows)
  const int wn = w & 3;                // 0..3 : 64-cout quarter
  const int fi = lane & 15;
  const int kc4 = lane >> 4;           // 0..3

  // ---- XCD swizzle, ctile-major (each XCD covers one ctile slice)
  const int bid = (int)blockIdx.x;
  const int logical = (bid & 7) * QXC + (bid >> 3);
  const int ptile = logical & 127;
  const int ctile = logical >> 7;
  const int p0 = ptile * 256;          // 4 consecutive out rows of one batch
  const int pb = p0 >> 12;             // batch (16 ptiles/batch, no cross)
  const int y0 = (p0 >> 6) & 63;       // first out row
  const int arowg = ((pb * 66 + y0) * 66) * 8;  // padded rows y0..y0+5

  floatx4 acc[8][4] = {};

  // ---- A staging: wave w owns kchunk w; 6 rows, 1056 B each (overlap trick)
  auto stageA = [&](int cg) {
    const unsigned short* g = Xp + (cg * 8 + w) * CPLANE + arowg + lane * 8;
    unsigned short* d = Abuf + w * AKS;
#pragma unroll
    for (int rr = 0; rr < 6; ++rr) {
      GLD(g + rr * 528,      d + rr * 528);        // shorts [0,512)
      GLD(g + rr * 528 + 16, d + rr * 528 + 16);   // shorts [16,528)
    }
  };
  // ---- B staging: wave w owns kchunk w; 256 couts = 4 x 1 KiB chunks
  auto stageB = [&](int tap, int cg, unsigned short* dst) {
    const unsigned short* g =
        Wg + ((tap * 64 + cg * 8 + w) * COUT + ctile * 256) * 8 + lane * 8;
    unsigned short* d = dst + w * BKS;
#pragma unroll
    for (int ch = 0; ch < 4; ++ch) GLD(g + ch * 512, d + ch * 512);
  };
  auto compute = [&](const unsigned short* Bsel, int dy, int dx) {
#pragma unroll
    for (int t = 0; t < 2; ++t) {
      const unsigned short* ab = Abuf + (kc4 + 4 * t) * AKS;
      short8 af[8];
#pragma unroll
      for (int mi = 0; mi < 8; ++mi)
        af[mi] = *(const short8*)(ab + (wm * 2 + (mi >> 2) + 1 + dy) * 528 +
                                  ((mi & 3) * 16 + fi + 1 + dx) * 8);
      const unsigned short* bb =
          Bsel + (kc4 + 4 * t) * BKS + (wn * 64 + fi) * 8;
      short8 bfr[4];
#pragma unroll
      for (int ni = 0; ni < 4; ++ni)
        bfr[ni] = *(const short8*)(bb + ni * 128);
#pragma unroll
      for (int mi = 0; mi < 8; ++mi)
#pragma unroll
        for (int ni = 0; ni < 4; ++ni)
          acc[mi][ni] = __builtin_amdgcn_mfma_f32_16x16x32_bf16(
              af[mi], bfr[ni], acc[mi][ni], 0, 0, 0);
    }
  };

  // ---- main loop (proven round-0 skeleton)
  int buf = 0;
  stageA(0);
  stageB(0, 0, Bbuf0);
  __syncthreads();
  for (int cg = 0; cg < 8; ++cg) {
#pragma unroll
    for (int tap = 0; tap < 9; ++tap) {
      unsigned short* cur = buf ? Bbuf1 : Bbuf0;
      unsigned short* nxt = buf ? Bbuf0 : Bbuf1;
      if (tap < 8)      stageB(tap + 1, cg, nxt);      // prefetch next tap
      else if (cg < 7)  stageB(0, cg + 1, nxt);        // prefetch next c-group
      compute(cur, tap / 3 - 1, tap % 3 - 1);
      __syncthreads();   // drains prefetch DMA (flew during MFMAs)
      buf ^= 1;
    }
    if (cg < 7) {
      stageA(cg + 1);    // A region free: all taps of cg done
      __syncthreads();
    }
  }

  // ---- epilogue: BN + ReLU
  // C/D layout: col = lane&15 (=cout), row = (lane>>4)*4 + reg (=pixel)
#pragma unroll
  for (int ni = 0; ni < 4; ++ni) {
    const int co = ctile * 256 + wn * 64 + ni * 16 + fi;
    const float sc = gamma[co] / sqrtf(var[co] + EPSV);
    const float sh2 = beta[co] - mean[co] * sc;
#pragma unroll
    for (int mi = 0; mi < 8; ++mi) {
      const int p = p0 + wm * 128 + mi * 16 + kc4 * 4;  // 4 consecutive px
      const int pbb = p >> 12;
      const int prem = p & 4095;
      if constexpr (FINAL) {
        floatx4 o;
#pragma unroll
        for (int r = 0; r < 4; ++r) o[r] = fmaxf(acc[mi][ni][r] * sc + sh2, 0.0f);
        *(floatx4*)(OutF + ((pbb * COUT + co) << 12) + prem) = o;  // NCHW fp32
      } else {
        const int py = prem >> 6, px = prem & 63;
        unsigned short* dst = OutPad + (co >> 3) * CPLANE +
            ((pbb * 66 + py + 1) * 66 + px + 1) * 8 + (co & 7);
#pragma unroll
        for (int r = 0; r < 4; ++r)
          dst[r * 8] = f2bf(fmaxf(acc[mi][ni][r] * sc + sh2, 0.0f));
      }
    }
  }
}

// ---------------------------------------------------------------------------
// Original implicit-GEMM conv (kept for conv1: COUT=256, CTILE=128,
// 2 blocks/CU). XCD-aware ctile-major swizzle, compile-time grid.
// ---------------------------------------------------------------------------
template <int COUT, int CTILE, bool FINAL>
__global__ __launch_bounds__(256) void conv3x3_kernel(
    const unsigned short* __restrict__ Xp, const unsigned short* __restrict__ Wg,
    const float* __restrict__ gamma, const float* __restrict__ beta,
    const float* __restrict__ mean, const float* __restrict__ var,
    unsigned short* __restrict__ OutPad, float* __restrict__ OutF) {
  constexpr int NCT = COUT / CTILE;
  constexpr int NI  = CTILE / 32;          // n-subtiles per wave
  constexpr int NWG = 256 * NCT;           // launched grid size (exact)
  constexpr int QXC = NWG / 8;             // blocks per XCD
  __shared__ unsigned short Abuf[16896];   // [kc 8][row 4][x 66][8] = 33 KiB
  __shared__ unsigned short Bbuf0[CTILE * 64];  // [kc 8][CTILE][8]
  __shared__ unsigned short Bbuf1[CTILE * 64];

  const int tid = threadIdx.x;
  const int bid = (int)blockIdx.x;
  const int logical = (bid & 7) * QXC + (bid >> 3);
  const int ptile = logical & 255;         // 256 ptiles (32768 px / 128)
  const int ctile = logical >> 8;
  const int p0 = ptile * 128;          // 2 consecutive y-rows of one batch
  const int w = tid >> 6;
  const int lane = tid & 63;

  const int pb = p0 >> 12;             // batch
  const int yb = (p0 >> 6) & 63;       // first input padded row (dy=-1)
  const int arowg = ((pb * 66 + yb) * 66) * 8;   // global elem offset of row 0

  const int fi = lane & 15;
  const int kc = lane >> 4;
  const int wm = w >> 1, wn = w & 1;
  const int aLane = kc * 2112 + (wm + 1) * 528 + (fi + 1) * 8;
  const int bLane = kc * CTILE * 8 + (wn * (CTILE / 2) + fi) * 8;

  floatx4 acc[4][NI] = {};

  auto stageA = [&](int cg) {
#pragma unroll
    for (int kk = 0; kk < 2; ++kk) {
      const int kc2 = 2 * w + kk;
      const unsigned short* g = Xp + (cg * 8 + kc2) * CPLANE + arowg + lane * 8;
      unsigned short* d = Abuf + kc2 * 2112;
#pragma unroll
      for (int rr = 0; rr < 4; ++rr) {
        GLD(g + rr * 528,      d + rr * 528);
        GLD(g + rr * 528 + 16, d + rr * 528 + 16);
      }
    }
  };
  auto stageB = [&](int tap, int cg, unsigned short* dst) {
#pragma unroll
    for (int kk = 0; kk < 2; ++kk) {
      const int kc2 = 2 * w + kk;
      const unsigned short* g =
          Wg + ((tap * 64 + cg * 8 + kc2) * COUT + ctile * CTILE + lane) * 8;
#pragma unroll
      for (int half = 0; half < CTILE / 64; ++half)
        GLD(g + half * 64 * 8, dst + (kc2 * CTILE + half * 64) * 8);
    }
  };
  auto compute = [&](const unsigned short* Bsel, int dy, int dx) {
#pragma unroll
    for (int t = 0; t < 2; ++t) {
      short8 af[4];
#pragma unroll
      for (int mi = 0; mi < 4; ++mi)
        af[mi] = *(const short8*)(Abuf + aLane + t * 8448 + dy * 528 +
                                  (mi * 16 + dx) * 8);
      short8 bfr[NI];
#pragma unroll
      for (int ni = 0; ni < NI; ++ni)
        bfr[ni] = *(const short8*)(Bsel + bLane + t * CTILE * 32 + ni * 128);
#pragma unroll
      for (int mi = 0; mi < 4; ++mi)
#pragma unroll
        for (int ni = 0; ni < NI; ++ni)
          acc[mi][ni] = __builtin_amdgcn_mfma_f32_16x16x32_bf16(
              af[mi], bfr[ni], acc[mi][ni], 0, 0, 0);
    }
  };

  int buf = 0;
  stageA(0);
  stageB(0, 0, Bbuf0);
  __syncthreads();
  for (int cg = 0; cg < 8; ++cg) {
#pragma unroll
    for (int tap = 0; tap < 9; ++tap) {
      unsigned short* cur = buf ? Bbuf1 : Bbuf0;
      unsigned short* nxt = buf ? Bbuf0 : Bbuf1;
      if (tap < 8)      stageB(tap + 1, cg, nxt);
      else if (cg < 7)  stageB(0, cg + 1, nxt);
      compute(cur, tap / 3 - 1, tap % 3 - 1);
      __syncthreads();
      buf ^= 1;
    }
    if (cg < 7) {
      stageA(cg + 1);
      __syncthreads();
    }
  }

#pragma unroll
  for (int ni = 0; ni < NI; ++ni) {
    const int co = ctile * CTILE + wn * (CTILE / 2) + ni * 16 + fi;
    const float sc = gamma[co] / sqrtf(var[co] + EPSV);
    const float sh2 = beta[co] - mean[co] * sc;
#pragma unroll
    for (int mi = 0; mi < 4; ++mi) {
      const int p = p0 + wm * 64 + mi * 16 + kc * 4;
      const int pbb = p >> 12;
      const int prem = p & 4095;
      if constexpr (FINAL) {
        floatx4 o;
#pragma unroll
        for (int r = 0; r < 4; ++r) o[r] = fmaxf(acc[mi][ni][r] * sc + sh2, 0.0f);
        *(floatx4*)(OutF + ((pbb * COUT + co) << 12) + prem) = o;
      } else {
        const int py = prem >> 6, px = prem & 63;
        unsigned short* dst = OutPad + (co >> 3) * CPLANE +
            ((pbb * 66 + py + 1) * 66 + px + 1) * 8 + (co & 7);
#pragma unroll
        for (int r = 0; r < 4; ++r)
          dst[r * 8] = f2bf(fmaxf(acc[mi][ni][r] * sc + sh2, 0.0f));
      }
    }
  }
}

// ---------------------------------------------------------------------------
// workspace layout (bytes):
//   Xp0 : 0          .. 35684352   (64cc * 8*66*66 * 8 bf16)
//   Xp1 : 35684352   .. 71368704
//   Wg0 : 71368704   .. 76087296   (9*64*512*8 bf16)
//   Wg1 : 76087296   .. 78446592   (9*64*256*8 bf16)
// ---------------------------------------------------------------------------
extern "C" void kernel_launch(void* const* d_in, const int* in_sizes, int n_in,
                              void* d_out, int out_size, void* d_ws, size_t ws_size,
                              hipStream_t stream) {
  const float* xt    = (const float*)d_in[0];
  const float* xm    = (const float*)d_in[1];
  const float* alpha = (const float*)d_in[3];
  const float* w0    = (const float*)d_in[4];
  const float* g0    = (const float*)d_in[5];
  const float* b0    = (const float*)d_in[6];
  const float* m0    = (const float*)d_in[7];
  const float* v0    = (const float*)d_in[8];
  const float* w1    = (const float*)d_in[9];
  const float* g1    = (const float*)d_in[10];
  const float* b1    = (const float*)d_in[11];
  const float* m1    = (const float*)d_in[12];
  const float* v1    = (const float*)d_in[13];
  float* out = (float*)d_out;

  char* ws = (char*)d_ws;
  unsigned short* Xp0 = (unsigned short*)(ws);
  unsigned short* Xp1 = (unsigned short*)(ws + 35684352);
  unsigned short* Wg0 = (unsigned short*)(ws + 2 * 35684352);
  unsigned short* Wg1 = (unsigned short*)(ws + 2 * 35684352 + 4718592);

  border_zero_kernel<<<520, 256, 0, stream>>>(Xp0, Xp1);
  prep_w_kernel<512><<<512, 256, 0, stream>>>(w0, Wg0);
  prep_w_kernel<256><<<256, 256, 0, stream>>>(w1, Wg1);
  fuse_upsample_kernel<<<8192, 256, 0, stream>>>(xt, xm, alpha, Xp0);
  conv3x3_fat_kernel<512, false><<<256, 512, 0, stream>>>(Xp0, Wg0, g0, b0, m0, v0, Xp1, nullptr);
  conv3x3_kernel<256, 128, true><<<512, 256, 0, stream>>>(Xp1, Wg1, g1, b1, m1, v1, nullptr, out);
}